// Round 1
// baseline (164.153 us; speedup 1.0000x reference)
//
#include <hip/hip_runtime.h>
#include <float.h>

// Problem constants (fixed by the reference): B=2, N=M=8192, G=256
#define B_ 2
#define N_ 8192
#define G_ 256
// CELL = abs(2*(-35)/256) = 70/256 = 0.2734375 exactly representable in fp32
constexpr float X_MIN_F = -35.0f;
constexpr float CELL_F  = 0.2734375f;

using u64 = unsigned long long;

// ---------------------------------------------------------------------------
// 1-NN (L1) kernel: for each row point in P, min/argmin of L1 distance over a
// column chunk of Q; combined globally via atomicMin on packed (dist|idx).
// grid: x = row-block (N/1024 = 8), y = col chunk (M/256 = 32), z = batch (2)
// Each thread owns 4 consecutive rows (register tiling amortizes LDS reads).
// ---------------------------------------------------------------------------
__global__ __launch_bounds__(256) void nn_kernel(const float* __restrict__ P,
                                                 const float* __restrict__ Q,
                                                 u64* __restrict__ out)
{
    const int b    = blockIdx.z;
    const int tid  = threadIdx.x;
    const int row0 = blockIdx.x * (256 * 4) + tid * 4;
    const int c0   = blockIdx.y * 256;

    __shared__ float qx[256], qy[256], qz[256];
    {
        const float* qp = Q + ((size_t)b * N_ + c0 + tid) * 3;
        float a0 = qp[0], a1 = qp[1], a2 = qp[2];
        qx[tid] = a0; qy[tid] = a1; qz[tid] = a2;
    }

    float px[4], py[4], pz[4];
    const float* pp = P + ((size_t)b * N_ + row0) * 3;
#pragma unroll
    for (int r = 0; r < 4; r++) {
        px[r] = pp[r * 3 + 0];
        py[r] = pp[r * 3 + 1];
        pz[r] = pp[r * 3 + 2];
    }

    float best[4]; int bidx[4];
#pragma unroll
    for (int r = 0; r < 4; r++) { best[r] = FLT_MAX; bidx[r] = c0; }

    __syncthreads();

#pragma unroll 4
    for (int j = 0; j < 256; j++) {
        float x = qx[j], y = qy[j], z = qz[j];
#pragma unroll
        for (int r = 0; r < 4; r++) {
            // bit-match reference: (|d0| + |d1|) + |d2|, left-assoc fp32
            float d = (fabsf(px[r] - x) + fabsf(py[r] - y)) + fabsf(pz[r] - z);
            bool lt = d < best[r];           // strict < keeps first occurrence
            best[r] = lt ? d : best[r];
            bidx[r] = lt ? (c0 + j) : bidx[r];
        }
    }

#pragma unroll
    for (int r = 0; r < 4; r++) {
        // non-negative fp32: bit pattern orders like unsigned. Ties -> min idx
        u64 pk = ((u64)__float_as_uint(best[r]) << 32) | (unsigned)bidx[r];
        atomicMin(&out[(size_t)b * N_ + row0 + r], pk);
    }
}

// ---------------------------------------------------------------------------
// Per-point label + scatter into the (B,G,G) grid.
// Last-write-wins in point order n  ==  max n wins  ->  atomicMax on
// packed (n<<1 | label); grid initialized to -1 (invalid).
// ---------------------------------------------------------------------------
__global__ __launch_bounds__(256) void scatter_kernel(
    const u64* __restrict__ chamx, const u64* __restrict__ chamy,
    const float* __restrict__ flow, const int* __restrict__ nflow,
    const float* __restrict__ Pj, int* __restrict__ grid)
{
    int i = blockIdx.x * 256 + threadIdx.x;      // i in [0, B*N)
    int b = i >> 13;                             // N = 8192
    int n = i & (N_ - 1);

    u64 pX = chamx[i];
    u64 pY = chamy[i];
    float dx = __uint_as_float((unsigned)(pX >> 32));
    float dy = __uint_as_float((unsigned)(pY >> 32));
    float rigid = (dx + dy) * 0.5f;

    bool dyn  = flow[i] > rigid;
    int label = dyn ? 1 : 0;
    int idx   = dyn ? nflow[i] : (int)(unsigned)(pX & 0xFFFFFFFFull);

    const float* q = Pj + ((size_t)b * N_ + idx) * 3;
    float x = q[0], y = q[1];

    // bit-match reference: (p - shift) / CELL with IEEE fp32 divide, trunc cast
    int cx = (int)((x - X_MIN_F) / CELL_F);
    int cy = (int)((y - X_MIN_F) / CELL_F);

    atomicMax(&grid[(b << 16) + cx * G_ + cy], (n << 1) | label);
}

// ---------------------------------------------------------------------------
// Cross-entropy over valid grid cells; accum[0] = sum(lp), accum[1] = count
// ---------------------------------------------------------------------------
__global__ __launch_bounds__(256) void ce_kernel(const float* __restrict__ mos,
                                                 const int* __restrict__ grid,
                                                 float* __restrict__ accum)
{
    int i = blockIdx.x * 256 + threadIdx.x;      // i in [0, B*G*G) = 131072
    float lsum = 0.0f;
    int   lcnt = 0;

    int packed = grid[i];
    if (packed >= 0) {
        int b    = i >> 16;                      // G*G = 65536
        int cell = i & 0xFFFF;
        float m0 = mos[((size_t)b * 2 + 0) * 65536 + cell];
        float m1 = mos[((size_t)b * 2 + 1) * 65536 + cell];
        float mx = fmaxf(m0, m1);
        float lse = logf(expf(m0 - mx) + expf(m1 - mx));
        float sh  = ((packed & 1) ? m1 : m0) - mx;   // stable log_softmax
        lsum = sh - lse;
        lcnt = 1;
    }

    // wave-64 shuffle reduction
#pragma unroll
    for (int o = 32; o > 0; o >>= 1) {
        lsum += __shfl_down(lsum, o);
        lcnt += __shfl_down(lcnt, o);
    }
    __shared__ float wsum[4];
    __shared__ int   wcnt[4];
    int wave = threadIdx.x >> 6;
    if ((threadIdx.x & 63) == 0) { wsum[wave] = lsum; wcnt[wave] = lcnt; }
    __syncthreads();
    if (threadIdx.x == 0) {
        float s = wsum[0] + wsum[1] + wsum[2] + wsum[3];
        int   c = wcnt[0] + wcnt[1] + wcnt[2] + wcnt[3];
        atomicAdd(&accum[0], s);
        atomicAdd((int*)&accum[1], c);
    }
}

__global__ void finalize_kernel(const float* __restrict__ accum,
                                float* __restrict__ out)
{
    float s = accum[0];
    int   c = ((const int*)accum)[1];
    out[0] = -s / (float)(c > 0 ? c : 1);
}

// ---------------------------------------------------------------------------
extern "C" void kernel_launch(void* const* d_in, const int* in_sizes, int n_in,
                              void* d_out, int out_size, void* d_ws, size_t ws_size,
                              hipStream_t stream)
{
    const float* p_i   = (const float*)d_in[0];   // (B,N,3)
    const float* mos   = (const float*)d_in[1];   // (B,2,G,G)
    const float* p_j   = (const float*)d_in[2];   // (B,M,3)
    const float* flow  = (const float*)d_in[3];   // (B,N)
    const int*   nflow = (const int*)d_in[4];     // (B,N,1)
    float* out = (float*)d_out;

    char* ws = (char*)d_ws;
    u64* chamx  = (u64*)(ws);                     // B*N u64  = 128 KB
    u64* chamy  = (u64*)(ws + 131072);            // B*N u64  = 128 KB
    int* grid   = (int*)(ws + 262144);            // B*G*G int = 512 KB
    float* accum = (float*)(ws + 786432);         // sum(float) + count(int)

    // init: 0xFF.. = u64-max for the packed mins AND -1 for the int grid
    hipMemsetAsync(ws, 0xFF, 786432, stream);
    hipMemsetAsync(ws + 786432, 0, 8, stream);

    dim3 g(N_ / (256 * 4), N_ / 256, B_);         // (8, 32, 2) = 512 blocks
    nn_kernel<<<g, 256, 0, stream>>>(p_i, p_j, chamx);   // cham_x + nearest_rigid
    nn_kernel<<<g, 256, 0, stream>>>(p_j, p_i, chamy);   // cham_y

    scatter_kernel<<<(B_ * N_) / 256, 256, 0, stream>>>(chamx, chamy, flow,
                                                        nflow, p_j, grid);
    ce_kernel<<<(B_ * G_ * G_) / 256, 256, 0, stream>>>(mos, grid, accum);
    finalize_kernel<<<1, 1, 0, stream>>>(accum, out);
}

// Round 2
// 144.445 us; speedup vs baseline: 1.1364x; 1.1364x over previous
//
#include <hip/hip_runtime.h>
#include <float.h>

// Problem constants (fixed by the reference): B=2, N=M=8192, G=256
#define B_ 2
#define N_ 8192
#define G_ 256
// CELL = abs(2*(-35)/256) = 70/256 = 0.2734375 exactly representable in fp32
constexpr float X_MIN_F = -35.0f;
constexpr float CELL_F  = 0.2734375f;

using u64 = unsigned long long;

// Workspace layout (bytes):
//   chamx  u64[B*N]      [0,      131072)   packed (distbits<<32)|idx
//   chamy  u32[B*N]      [131072, 196608)   distbits only (argmin unused)
//   grid   i32[B*G*G]    [196608, 720896)   packed (n<<1)|label, -1 invalid
//   accum  16B           [720896, 720912)   {float sum, int cnt, uint ticket, pad}
#define OFF_CHAMY 131072
#define OFF_GRID  196608
#define OFF_ACCUM 720896

// ---------------------------------------------------------------------------
// init: 0xFFFFFFFF over chamx/chamy/grid (u64-max for mins, -1 for grid),
// zeros over accum. One dispatch replaces two hipMemsetAsync.
// ---------------------------------------------------------------------------
__global__ __launch_bounds__(256) void init_kernel(uint4* __restrict__ ws)
{
    int i = blockIdx.x * 256 + threadIdx.x;
    if (i < 45056)       ws[i] = make_uint4(~0u, ~0u, ~0u, ~0u);
    else if (i == 45056) ws[i] = make_uint4(0u, 0u, 0u, 0u);   // accum
}

// ---------------------------------------------------------------------------
// 1-NN (L1): rows of P vs a 128-column chunk of Q staged in LDS (tight xyz
// pack, read back as float4 -> ds_read_b128, same-address broadcast).
// 4 rows/thread register tiling. NEED_IDX tracks argmin (first occurrence);
// otherwise pure fminf (reference discards the y-direction argmin).
// grid: (N/1024, M/128, B) = (8, 64, 2) = 1024 blocks -> 16 waves/CU.
// ---------------------------------------------------------------------------
template<bool NEED_IDX>
__global__ __launch_bounds__(256) void nn_kernel(const float* __restrict__ P,
                                                 const float* __restrict__ Q,
                                                 u64* __restrict__ outp,
                                                 unsigned* __restrict__ outd)
{
    const int b    = blockIdx.z;
    const int tid  = threadIdx.x;
    const int row0 = blockIdx.x * 1024 + tid * 4;
    const int c0   = blockIdx.y * 128;

    __shared__ __align__(16) float q[128 * 3];
    if (tid < 96)
        ((float4*)q)[tid] = ((const float4*)(Q + ((size_t)b * N_ + c0) * 3))[tid];

    // 4 consecutive rows = 12 consecutive floats = 3 float4
    const float4* pp = (const float4*)(P + ((size_t)b * N_ + row0) * 3);
    float4 r0 = pp[0], r1 = pp[1], r2 = pp[2];
    float px[4] = {r0.x, r0.w, r1.z, r2.y};
    float py[4] = {r0.y, r1.x, r1.w, r2.z};
    float pz[4] = {r0.z, r1.y, r2.x, r2.w};

    float best[4]; int bidx[4];
#pragma unroll
    for (int r = 0; r < 4; r++) { best[r] = FLT_MAX; bidx[r] = c0; }

    __syncthreads();

    for (int j4 = 0; j4 < 128; j4 += 4) {
        float4 a  = *(const float4*)&q[j4 * 3];
        float4 bb = *(const float4*)&q[j4 * 3 + 4];
        float4 cc = *(const float4*)&q[j4 * 3 + 8];
        float qxs[4] = {a.x, a.w, bb.z, cc.y};
        float qys[4] = {a.y, bb.x, bb.w, cc.z};
        float qzs[4] = {a.z, bb.y, cc.x, cc.w};
#pragma unroll
        for (int k = 0; k < 4; k++) {
#pragma unroll
            for (int r = 0; r < 4; r++) {
                // bit-match reference: (|d0| + |d1|) + |d2|, left-assoc fp32
                float d = (fabsf(px[r] - qxs[k]) + fabsf(py[r] - qys[k]))
                          + fabsf(pz[r] - qzs[k]);
                if (NEED_IDX) {
                    bool lt = d < best[r];       // strict < -> first occurrence
                    best[r] = lt ? d : best[r];
                    bidx[r] = lt ? (c0 + j4 + k) : bidx[r];
                } else {
                    best[r] = fminf(best[r], d);
                }
            }
        }
    }

#pragma unroll
    for (int r = 0; r < 4; r++) {
        if (NEED_IDX) {
            // non-negative fp32 bits order like unsigned; ties -> min idx
            u64 pk = ((u64)__float_as_uint(best[r]) << 32) | (unsigned)bidx[r];
            atomicMin(&outp[(size_t)b * N_ + row0 + r], pk);
        } else {
            atomicMin(&outd[(size_t)b * N_ + row0 + r], __float_as_uint(best[r]));
        }
    }
}

// ---------------------------------------------------------------------------
// Per-point label + scatter into the (B,G,G) grid.
// Last-write-wins in point order n == max n wins -> atomicMax on
// packed (n<<1 | label); grid initialized to -1 (invalid).
// ---------------------------------------------------------------------------
__global__ __launch_bounds__(256) void scatter_kernel(
    const u64* __restrict__ chamx, const unsigned* __restrict__ chamy,
    const float* __restrict__ flow, const int* __restrict__ nflow,
    const float* __restrict__ Pj, int* __restrict__ grid)
{
    int i = blockIdx.x * 256 + threadIdx.x;      // i in [0, B*N)
    int b = i >> 13;                             // N = 8192
    int n = i & (N_ - 1);

    u64 pX = chamx[i];
    float dx = __uint_as_float((unsigned)(pX >> 32));
    float dy = __uint_as_float(chamy[i]);
    float rigid = (dx + dy) * 0.5f;

    bool dyn  = flow[i] > rigid;
    int label = dyn ? 1 : 0;
    int idx   = dyn ? nflow[i] : (int)(unsigned)(pX & 0xFFFFFFFFull);

    const float* qp = Pj + ((size_t)b * N_ + idx) * 3;
    float x = qp[0], y = qp[1];

    // bit-match reference: (p - shift) / CELL, IEEE fp32 divide, trunc cast
    int cx = (int)((x - X_MIN_F) / CELL_F);
    int cy = (int)((y - X_MIN_F) / CELL_F);

    atomicMax(&grid[(b << 16) + cx * G_ + cy], (n << 1) | label);
}

// ---------------------------------------------------------------------------
// Cross-entropy over valid grid cells + fused finalize: last block (ticket)
// reads the device-scope accumulators and writes the loss.
// ---------------------------------------------------------------------------
__global__ __launch_bounds__(256) void ce_kernel(const float* __restrict__ mos,
                                                 const int* __restrict__ grid,
                                                 float* __restrict__ accum,
                                                 float* __restrict__ out)
{
    int i = blockIdx.x * 256 + threadIdx.x;      // i in [0, B*G*G) = 131072
    float lsum = 0.0f;
    int   lcnt = 0;

    int packed = grid[i];
    if (packed >= 0) {
        int b    = i >> 16;                      // G*G = 65536
        int cell = i & 0xFFFF;
        float m0 = mos[((size_t)b * 2 + 0) * 65536 + cell];
        float m1 = mos[((size_t)b * 2 + 1) * 65536 + cell];
        float mx = fmaxf(m0, m1);
        float lse = logf(expf(m0 - mx) + expf(m1 - mx));
        float sh  = ((packed & 1) ? m1 : m0) - mx;   // stable log_softmax
        lsum = sh - lse;
        lcnt = 1;
    }

    // wave-64 shuffle reduction
#pragma unroll
    for (int o = 32; o > 0; o >>= 1) {
        lsum += __shfl_down(lsum, o);
        lcnt += __shfl_down(lcnt, o);
    }
    __shared__ float wsum[4];
    __shared__ int   wcnt[4];
    int wave = threadIdx.x >> 6;
    if ((threadIdx.x & 63) == 0) { wsum[wave] = lsum; wcnt[wave] = lcnt; }
    __syncthreads();
    if (threadIdx.x == 0) {
        float s = wsum[0] + wsum[1] + wsum[2] + wsum[3];
        int   c = wcnt[0] + wcnt[1] + wcnt[2] + wcnt[3];
        atomicAdd(&accum[0], s);
        atomicAdd((int*)&accum[1], c);
        __threadfence();
        unsigned t = atomicAdd((unsigned*)&accum[2], 1u);
        if (t == gridDim.x - 1) {
            // device-scope RMW reads see all prior adds (same-address order)
            float S = atomicAdd(&accum[0], 0.0f);
            int   C = atomicAdd((int*)&accum[1], 0);
            out[0] = -S / (float)(C > 0 ? C : 1);
        }
    }
}

// ---------------------------------------------------------------------------
extern "C" void kernel_launch(void* const* d_in, const int* in_sizes, int n_in,
                              void* d_out, int out_size, void* d_ws, size_t ws_size,
                              hipStream_t stream)
{
    const float* p_i   = (const float*)d_in[0];   // (B,N,3)
    const float* mos   = (const float*)d_in[1];   // (B,2,G,G)
    const float* p_j   = (const float*)d_in[2];   // (B,M,3)
    const float* flow  = (const float*)d_in[3];   // (B,N)
    const int*   nflow = (const int*)d_in[4];     // (B,N,1)
    float* out = (float*)d_out;

    char* ws = (char*)d_ws;
    u64*      chamx = (u64*)(ws);
    unsigned* chamy = (unsigned*)(ws + OFF_CHAMY);
    int*      grid  = (int*)(ws + OFF_GRID);
    float*    accum = (float*)(ws + OFF_ACCUM);

    init_kernel<<<177, 256, 0, stream>>>((uint4*)ws);

    dim3 g(N_ / 1024, N_ / 128, B_);              // (8, 64, 2) = 1024 blocks
    nn_kernel<true ><<<g, 256, 0, stream>>>(p_i, p_j, chamx, nullptr); // cham_x + argmin
    nn_kernel<false><<<g, 256, 0, stream>>>(p_j, p_i, nullptr, chamy); // cham_y

    scatter_kernel<<<(B_ * N_) / 256, 256, 0, stream>>>(chamx, chamy, flow,
                                                        nflow, p_j, grid);
    ce_kernel<<<(B_ * G_ * G_) / 256, 256, 0, stream>>>(mos, grid, accum, out);
}